// Round 4
// baseline (187.799 us; speedup 1.0000x reference)
//
#include <hip/hip_runtime.h>
#include <hip/hip_bf16.h>
#include <stdint.h>

// B=2, T=4096, C=512, H=8, D=64. Inputs fp32, output fp32, internals bf16.
// ws (bf16 elems), 32 MiB:
//   Q  [0        .. 4194304)   [B,H,T,D]  (pre-scaled by 0.125*log2e)
//   K  [4194304  .. 8388608)   [B,H,T,D]
//   Vt [8388608  .. 12582912)  [B,H,D,T]
//   Y  [12582912 .. 16777216)  [B,T,C]    (WaT here during QKV; clobbered by attn)
// WpT -> Q region after attn (Q dead). xb (x bf16) in d_out until proj overwrites.

typedef __attribute__((ext_vector_type(8))) short short8;
typedef __attribute__((ext_vector_type(4))) float floatx4;
typedef __attribute__((ext_vector_type(16))) float floatx16;
#if __has_builtin(__builtin_amdgcn_permlane32_swap)
typedef __attribute__((ext_vector_type(2))) unsigned int uint2v;
#define HAVE_PLSWAP 1
#else
#define HAVE_PLSWAP 0
#endif

__device__ __forceinline__ unsigned short f2bf(float f) {
    unsigned int x = __float_as_uint(f);
    unsigned int r = x + 0x7fffu + ((x >> 16) & 1u);
    return (unsigned short)(r >> 16);
}

__device__ __forceinline__ unsigned int pk_bf16(float a, float b) {
    __hip_bfloat162 p = __float22bfloat162_rn(make_float2(a, b));  // v_cvt_pk_bf16_f32
    return *reinterpret_cast<unsigned int*>(&p);
}

// sum of the two bf16 values packed in w (exactly the values PV will consume)
__device__ __forceinline__ float bfsum2(unsigned int w) {
    return __uint_as_float(w << 16) + __uint_as_float(w & 0xffff0000u);
}

// ---------------- P0: fused prep: convert x (blocks 0..2047) + W_attn^T (2048..2815) --
__global__ __launch_bounds__(256) void prep_a(
    const float* __restrict__ x, unsigned short* __restrict__ xb,
    const float* __restrict__ Wa, unsigned short* __restrict__ WaT)
{
    const int bid = blockIdx.x;
    const int tid = threadIdx.x;
    if (bid < 2048) {
        size_t i = ((size_t)bid * 256 + tid) * 8;
        float4 a = *reinterpret_cast<const float4*>(x + i);
        float4 b = *reinterpret_cast<const float4*>(x + i + 4);
        unsigned short o[8] = {f2bf(a.x), f2bf(a.y), f2bf(a.z), f2bf(a.w),
                               f2bf(b.x), f2bf(b.y), f2bf(b.z), f2bf(b.w)};
        *reinterpret_cast<uint4*>(xb + i) = *reinterpret_cast<uint4*>(o);
    } else {
        __shared__ unsigned short tile[32][34];
        const int t2 = bid - 2048;           // 48 n-tiles x 16 k-tiles
        const int n0 = (t2 % 48) * 32, k0 = (t2 / 48) * 32;
        const int tx = tid & 31, ty = tid >> 5;
        #pragma unroll
        for (int p = 0; p < 4; ++p)
            tile[tx][ty + p * 8] = f2bf(Wa[(size_t)(k0 + ty + p * 8) * 1536 + n0 + tx]);
        __syncthreads();
        #pragma unroll
        for (int p = 0; p < 4; ++p)
            WaT[(size_t)(n0 + ty + p * 8) * 512 + k0 + tx] = tile[ty + p * 8][tx];
    }
}

// ---------------- P1: W_proj [512][512] fp32 -> WpT [512][512] bf16 -------------------
__global__ __launch_bounds__(256) void transpose_wp(
    const float* __restrict__ W, unsigned short* __restrict__ Wt)
{
    __shared__ unsigned short tile[32][34];
    const int tid = threadIdx.x;
    const int tx = tid & 31, ty = tid >> 5;
    const int n0 = blockIdx.x * 32, k0 = blockIdx.y * 32;
    #pragma unroll
    for (int p = 0; p < 4; ++p)
        tile[tx][ty + p * 8] = f2bf(W[(size_t)(k0 + ty + p * 8) * 512 + n0 + tx]);
    __syncthreads();
    #pragma unroll
    for (int p = 0; p < 4; ++p)
        Wt[(size_t)(n0 + ty + p * 8) * 512 + k0 + tx] = tile[ty + p * 8][tx];
}

// ---------------- MFMA GEMM (r16-proven): 128x128, BK=32, LDS dbuf, 1 barrier/iter ----
template<int EPI>
__global__ __launch_bounds__(256) void mm_bt(
    const unsigned short* __restrict__ A,
    const unsigned short* __restrict__ Bt,
    void* __restrict__ outp)
{
    __shared__ __align__(16) unsigned char smem[40960];

    const int tid  = threadIdx.x;
    const int wave = tid >> 6;
    const int lane = tid & 63;
    const int quad = lane >> 4;
    const int l16  = lane & 15;
    const int wr   = wave >> 1;
    const int wc   = wave & 1;
    const int m0 = blockIdx.x * 128;
    const int n0 = blockIdx.y * 128;

    floatx4 acc[4][4];
    #pragma unroll
    for (int i = 0; i < 4; ++i)
        #pragma unroll
        for (int j = 0; j < 4; ++j) acc[i][j] = (floatx4){0.f, 0.f, 0.f, 0.f};

    const int row = tid >> 1;
    const int cb  = (tid & 1) * 16;

    const unsigned short* ap = &A[(size_t)(m0 + row) * 512 + cb];
    const unsigned short* bp = &Bt[(size_t)(n0 + row) * 512 + cb];

    uint4 ra0 = *reinterpret_cast<const uint4*>(ap);
    uint4 ra1 = *reinterpret_cast<const uint4*>(ap + 8);
    uint4 rb0 = *reinterpret_cast<const uint4*>(bp);
    uint4 rb1 = *reinterpret_cast<const uint4*>(bp + 8);
    {
        auto Al = reinterpret_cast<unsigned short(*)[40]>(smem);
        auto Bl = reinterpret_cast<unsigned short(*)[40]>(smem + 10240);
        *reinterpret_cast<uint4*>(&Al[row][cb])     = ra0;
        *reinterpret_cast<uint4*>(&Al[row][cb + 8]) = ra1;
        *reinterpret_cast<uint4*>(&Bl[row][cb])     = rb0;
        *reinterpret_cast<uint4*>(&Bl[row][cb + 8]) = rb1;
    }

    for (int it = 0; it < 16; ++it) {
        __syncthreads();
        const int k0 = it * 32;
        if (it < 15) {
            ra0 = *reinterpret_cast<const uint4*>(ap + k0 + 32);
            ra1 = *reinterpret_cast<const uint4*>(ap + k0 + 40);
            rb0 = *reinterpret_cast<const uint4*>(bp + k0 + 32);
            rb1 = *reinterpret_cast<const uint4*>(bp + k0 + 40);
        }

        auto Al = reinterpret_cast<unsigned short(*)[40]>(smem + (it & 1) * 20480);
        auto Bl = reinterpret_cast<unsigned short(*)[40]>(smem + (it & 1) * 20480 + 10240);

        short8 af[4], bf[4];
        #pragma unroll
        for (int ti = 0; ti < 4; ++ti)
            af[ti] = *reinterpret_cast<const short8*>(&Al[wr * 64 + ti * 16 + l16][quad * 8]);
        #pragma unroll
        for (int tj = 0; tj < 4; ++tj)
            bf[tj] = *reinterpret_cast<const short8*>(&Bl[wc * 64 + tj * 16 + l16][quad * 8]);
        #pragma unroll
        for (int ti = 0; ti < 4; ++ti)
            #pragma unroll
            for (int tj = 0; tj < 4; ++tj)
                acc[ti][tj] = __builtin_amdgcn_mfma_f32_16x16x32_bf16(af[ti], bf[tj], acc[ti][tj], 0, 0, 0);

        if (it < 15) {
            auto An = reinterpret_cast<unsigned short(*)[40]>(smem + ((it + 1) & 1) * 20480);
            auto Bn = reinterpret_cast<unsigned short(*)[40]>(smem + ((it + 1) & 1) * 20480 + 10240);
            *reinterpret_cast<uint4*>(&An[row][cb])     = ra0;
            *reinterpret_cast<uint4*>(&An[row][cb + 8]) = ra1;
            *reinterpret_cast<uint4*>(&Bn[row][cb])     = rb0;
            *reinterpret_cast<uint4*>(&Bn[row][cb + 8]) = rb1;
        }
    }

    if (EPI == 0) {
        unsigned short* WS = (unsigned short*)outp;
        unsigned short* Qb  = WS;
        unsigned short* Kb  = WS + 4194304;
        unsigned short* Vtb = WS + 8388608;
        const int which = n0 >> 9;
        const int h = ((n0 + wc * 64) >> 6) & 7;

        if (which == 2) {
            auto Tr = reinterpret_cast<unsigned short(*)[80]>(smem);   // [256][80]
            __syncthreads();
            #pragma unroll
            for (int ti = 0; ti < 4; ++ti)
                #pragma unroll
                for (int tj = 0; tj < 4; ++tj) {
                    unsigned int lo = pk_bf16(acc[ti][tj][0], acc[ti][tj][1]);
                    unsigned int hi = pk_bf16(acc[ti][tj][2], acc[ti][tj][3]);
                    *reinterpret_cast<uint2*>(&Tr[(wave << 6) + tj * 16 + l16][ti * 16 + quad * 4])
                        = make_uint2(lo, hi);
                }
            const int b = m0 >> 12;
            const int bh = b * 8 + h;
            const int t0g = (m0 & 4095) + wr * 64;
            const int tseg = (lane & 7) * 8;
            #pragma unroll
            for (int p = 0; p < 8; ++p) {
                int dl = p * 8 + (lane >> 3);
                uint4 v = *reinterpret_cast<const uint4*>(&Tr[(wave << 6) + dl][tseg]);
                *reinterpret_cast<uint4*>(&Vtb[((size_t)(bh * 64 + dl)) * 4096 + t0g + tseg]) = v;
            }
        } else {
            const float sc = (which == 0) ? 0.18033688f : 1.0f;  // 0.125*log2(e)
            #pragma unroll
            for (int ti = 0; ti < 4; ++ti) {
                #pragma unroll
                for (int r = 0; r < 4; ++r) {
                    int m = m0 + wr * 64 + ti * 16 + quad * 4 + r;
                    int b = m >> 12, t = m & 4095;
                    int bh = b * 8 + h;
                    #pragma unroll
                    for (int tj = 0; tj < 4; ++tj) {
                        int d = tj * 16 + l16;
                        unsigned short val = f2bf(acc[ti][tj][r] * sc);
                        if (which == 0) Qb[((size_t)bh * 4096 + t) * 64 + d] = val;
                        else            Kb[((size_t)bh * 4096 + t) * 64 + d] = val;
                    }
                }
            }
        }
    } else {
        float* Out = (float*)outp;
        #pragma unroll
        for (int ti = 0; ti < 4; ++ti) {
            #pragma unroll
            for (int r = 0; r < 4; ++r) {
                int m = m0 + wr * 64 + ti * 16 + quad * 4 + r;
                #pragma unroll
                for (int tj = 0; tj < 4; ++tj) {
                    int n = n0 + wc * 64 + tj * 16 + l16;
                    Out[(size_t)m * 512 + n] = acc[ti][tj][r];
                }
            }
        }
    }
}

// ---------------- MFMA flash attention: 32x32x16, in-register P, paired q-blocks ------
// Block = 4 waves x 32 q-rows = two 64-row q-groups (qb = i for waves 0,1; qb = 63-i
// for waves 2,3). Loop kt = 0..63-i. Per-block wave-tile count = 2(64-i)+2(i+1) = 130
// CONSTANT -> per-CU work identical (2 blocks/CU, grid 512 = bid/bid+256 pair (u,31-u)).
// LDS traffic halved vs 16x16 path: 32 q-rows reuse each K/V fragment at register level
// (8 K + 8 V ds_read_b128 per 64-key tile per wave). P never touches LDS: S C-frag
// (q = lane&31 col-local) -> cvt_pk_bf16 -> permlane32_swap -> PV A-frags in registers.
// Rowsum = in-lane sum of the SAME packed bf16 words (numerically = old ones-MFMA) +
// one shfl_xor(32); redistributed to C-frag rows via a 128B/wave LDS bounce at the end.
// Layouts (32x32x16): A row=lane&31, k=(lane>>5)*8+j; B col=lane&31, same k;
// C row=(reg&3)+8*(reg>>2)+4*(lane>>5), col=lane&31 (guide m74/m101).
__global__ __launch_bounds__(256) void attn_mfma(
    const unsigned short* __restrict__ Q,
    const unsigned short* __restrict__ K,
    const unsigned short* __restrict__ Vt,
    unsigned short* __restrict__ Y)
{
    __shared__ __align__(16) unsigned short Kc[2][64][64];
    __shared__ __align__(16) unsigned short Vc[2][64][64];
    __shared__ __align__(16) float Ws[4][32];

    const int tid  = threadIdx.x;
    const int wave = tid >> 6;
    const int lane = tid & 63;
    const int l32  = lane & 31;
    const int hh   = lane >> 5;
    const int sw7  = lane & 7;

    const int bid = blockIdx.x;
    const int bh  = bid & 15;
    const int u   = (bid >> 4) & 15;
    const int ilo = (bid >> 8) ? (31 - u) : u;   // bid & bid+256 -> complementary pair
    const int ihi = 63 - ilo;
    const int qbw = (wave < 2) ? ilo : ihi;      // this wave's 64-row q-group
    const int qg0 = qbw * 64 + (wave & 1) * 32;  // wave's first q row in head

    const unsigned short* Qp = Q  + (size_t)bh * (4096 * 64);
    const unsigned short* Kp = K  + (size_t)bh * (4096 * 64);
    const unsigned short* Vp = Vt + (size_t)bh * (64 * 4096);

    // Q B-frags (pre-scaled upstream): col q = qg0+l32, k(d) = k16*16 + hh*8 + j
    short8 qf[4];
    #pragma unroll
    for (int k16 = 0; k16 < 4; ++k16)
        qf[k16] = *reinterpret_cast<const short8*>(
            &Qp[(size_t)(qg0 + l32) * 64 + k16 * 16 + hh * 8]);

    floatx16 o0 = {0,0,0,0,0,0,0,0,0,0,0,0,0,0,0,0};
    floatx16 o1 = {0,0,0,0,0,0,0,0,0,0,0,0,0,0,0,0};
    float rs = 0.f;

    // staging: thread covers rows rr, rr+32 at 16B chunk cc; XOR-swizzled (r1/r2-proven)
    const int rr  = tid >> 3;
    const int cc  = tid & 7;
    const int c0  = cc * 8;
    const int scs = ((cc ^ (rr & 7)) << 3);

    uint4 rk0 = *reinterpret_cast<const uint4*>(&Kp[(size_t)rr * 64 + c0]);
    uint4 rk1 = *reinterpret_cast<const uint4*>(&Kp[(size_t)(rr + 32) * 64 + c0]);
    uint4 rv0 = *reinterpret_cast<const uint4*>(&Vp[(size_t)rr * 4096 + c0]);
    uint4 rv1 = *reinterpret_cast<const uint4*>(&Vp[(size_t)(rr + 32) * 4096 + c0]);
    *reinterpret_cast<uint4*>(&Kc[0][rr][scs])      = rk0;
    *reinterpret_cast<uint4*>(&Kc[0][rr + 32][scs]) = rk1;
    *reinterpret_cast<uint4*>(&Vc[0][rr][scs])      = rv0;
    *reinterpret_cast<uint4*>(&Vc[0][rr + 32][scs]) = rv1;

    const int NT = ihi + 1;
    for (int kt = 0; kt < NT; ++kt) {
        __syncthreads();
        const int cur = kt & 1;
        const int nxt = cur ^ 1;

        if (kt + 1 < NT) {   // prefetch next tile into registers
            const int jn = (kt + 1) * 64;
            rk0 = *reinterpret_cast<const uint4*>(&Kp[(size_t)(jn + rr) * 64 + c0]);
            rk1 = *reinterpret_cast<const uint4*>(&Kp[(size_t)(jn + rr + 32) * 64 + c0]);
            rv0 = *reinterpret_cast<const uint4*>(&Vp[(size_t)rr * 4096 + jn + c0]);
            rv1 = *reinterpret_cast<const uint4*>(&Vp[(size_t)(rr + 32) * 4096 + jn + c0]);
        }

        if (kt <= qbw) {
            // ---- QK^T: S[key][q], A = K rows (l32 / 32+l32), B = Q ----
            floatx16 s0 = {0,0,0,0,0,0,0,0,0,0,0,0,0,0,0,0};
            floatx16 s1 = {0,0,0,0,0,0,0,0,0,0,0,0,0,0,0,0};
            #pragma unroll
            for (int k16 = 0; k16 < 4; ++k16) {
                const int chs = ((k16 * 2 + hh) ^ sw7) << 3;
                short8 a0 = *reinterpret_cast<const short8*>(&Kc[cur][l32][chs]);
                short8 a1 = *reinterpret_cast<const short8*>(&Kc[cur][32 + l32][chs]);
                s0 = __builtin_amdgcn_mfma_f32_32x32x16_bf16(a0, qf[k16], s0, 0, 0, 0);
                s1 = __builtin_amdgcn_mfma_f32_32x32x16_bf16(a1, qf[k16], s1, 0, 0, 0);
            }
            if (kt == qbw) {   // diagonal: key_local = (r&3)+8*(r>>2)+4*hh (+32 for s1)
                const int ql = (wave & 1) * 32 + l32;
                #pragma unroll
                for (int r = 0; r < 16; ++r) {
                    const int kl = (r & 3) + 8 * (r >> 2) + 4 * hh;
                    s0[r] = (kl      <= ql) ? s0[r] : -1e30f;
                    s1[r] = (kl + 32 <= ql) ? s1[r] : -1e30f;
                }
            }
            #pragma unroll
            for (int r = 0; r < 16; ++r) {
                s0[r] = __builtin_amdgcn_exp2f(s0[r]);
                s1[r] = __builtin_amdgcn_exp2f(s1[r]);
            }

            // ---- P -> PV A-frags in registers (cvt_pk + permlane32_swap / shfl) ----
            short8 pa[4];
            #pragma unroll
            for (int t = 0; t < 2; ++t) {
                float e0  = t ? s1[0]  : s0[0],  e1  = t ? s1[1]  : s0[1];
                float e2  = t ? s1[2]  : s0[2],  e3  = t ? s1[3]  : s0[3];
                float e4  = t ? s1[4]  : s0[4],  e5  = t ? s1[5]  : s0[5];
                float e6  = t ? s1[6]  : s0[6],  e7  = t ? s1[7]  : s0[7];
                float e8  = t ? s1[8]  : s0[8],  e9  = t ? s1[9]  : s0[9];
                float e10 = t ? s1[10] : s0[10], e11 = t ? s1[11] : s0[11];
                float e12 = t ? s1[12] : s0[12], e13 = t ? s1[13] : s0[13];
                float e14 = t ? s1[14] : s0[14], e15 = t ? s1[15] : s0[15];
                unsigned int A0 = pk_bf16(e0, e1),   B0 = pk_bf16(e2, e3);
                unsigned int A1 = pk_bf16(e4, e5),   B1 = pk_bf16(e6, e7);
                unsigned int A2 = pk_bf16(e8, e9),   B2 = pk_bf16(e10, e11);
                unsigned int A3 = pk_bf16(e12, e13), B3 = pk_bf16(e14, e15);
                rs += bfsum2(A0) + bfsum2(B0) + bfsum2(A1) + bfsum2(B1)
                    + bfsum2(A2) + bfsum2(B2) + bfsum2(A3) + bfsum2(B3);
#if HAVE_PLSWAP
                uint2v rA = __builtin_amdgcn_permlane32_swap(A0, A1, false, false);
                uint2v rB = __builtin_amdgcn_permlane32_swap(B0, B1, false, false);
                uint4 u0 = make_uint4(rA[0], rB[0], rA[1], rB[1]);
                pa[t * 2] = *reinterpret_cast<short8*>(&u0);
                rA = __builtin_amdgcn_permlane32_swap(A2, A3, false, false);
                rB = __builtin_amdgcn_permlane32_swap(B2, B3, false, false);
                uint4 u1 = make_uint4(rA[0], rB[0], rA[1], rB[1]);
                pa[t * 2 + 1] = *reinterpret_cast<short8*>(&u1);
#else
                unsigned int pA0 = __shfl_xor((int)A0, 32), pA1 = __shfl_xor((int)A1, 32);
                unsigned int pB0 = __shfl_xor((int)B0, 32), pB1 = __shfl_xor((int)B1, 32);
                unsigned int pA2 = __shfl_xor((int)A2, 32), pA3 = __shfl_xor((int)A3, 32);
                unsigned int pB2 = __shfl_xor((int)B2, 32), pB3 = __shfl_xor((int)B3, 32);
                uint4 u0 = make_uint4(hh ? pA1 : A0, hh ? pB1 : B0,
                                      hh ? A1 : pA0, hh ? B1 : pB0);
                pa[t * 2] = *reinterpret_cast<short8*>(&u0);
                uint4 u1 = make_uint4(hh ? pA3 : A2, hh ? pB3 : B2,
                                      hh ? A3 : pA2, hh ? B3 : pB2);
                pa[t * 2 + 1] = *reinterpret_cast<short8*>(&u1);
#endif
            }

            // ---- PV: O[q][d], A = P frags, B = V rows d (l32 / 32+l32) ----
            #pragma unroll
            for (int f = 0; f < 4; ++f) {
                const int chs = ((f * 2 + hh) ^ sw7) << 3;
                short8 b0 = *reinterpret_cast<const short8*>(&Vc[cur][l32][chs]);
                short8 b1 = *reinterpret_cast<const short8*>(&Vc[cur][32 + l32][chs]);
                o0 = __builtin_amdgcn_mfma_f32_32x32x16_bf16(pa[f], b0, o0, 0, 0, 0);
                o1 = __builtin_amdgcn_mfma_f32_32x32x16_bf16(pa[f], b1, o1, 0, 0, 0);
            }
        }

        if (kt + 1 < NT) {   // stage prefetched tile into the idle buffer
            *reinterpret_cast<uint4*>(&Kc[nxt][rr][scs])      = rk0;
            *reinterpret_cast<uint4*>(&Kc[nxt][rr + 32][scs]) = rk1;
            *reinterpret_cast<uint4*>(&Vc[nxt][rr][scs])      = rv0;
            *reinterpret_cast<uint4*>(&Vc[nxt][rr + 32][scs]) = rv1;
        }
    }

    // ---- rowsum combine + redistribute to C-frag rows, normalize, store ----
    float tot = rs + __shfl_xor(rs, 32);
    if (lane < 32) Ws[wave][l32] = 1.0f / tot;
    __syncthreads();

    float4 iv[4];
    #pragma unroll
    for (int g = 0; g < 4; ++g)
        iv[g] = *reinterpret_cast<const float4*>(&Ws[wave][g * 8 + hh * 4]);

    const int b = bh >> 3, h = bh & 7;
    #pragma unroll
    for (int g = 0; g < 4; ++g) {
        #pragma unroll
        for (int rsub = 0; rsub < 4; ++rsub) {
            const int r = g * 4 + rsub;
            const int t = qg0 + 8 * g + 4 * hh + rsub;
            const float sc = iv[g][rsub];
            unsigned short* yr = &Y[((size_t)(b * 4096 + t)) * 512 + h * 64];
            yr[l32]      = f2bf(o0[r] * sc);
            yr[32 + l32] = f2bf(o1[r] * sc);
        }
    }
}

extern "C" void kernel_launch(void* const* d_in, const int* in_sizes, int n_in,
                              void* d_out, int out_size, void* d_ws, size_t ws_size,
                              hipStream_t stream) {
    const float* x  = (const float*)d_in[0];
    const float* Wa = (const float*)d_in[1];
    const float* Wp = (const float*)d_in[2];
    float* out = (float*)d_out;
    unsigned short* ws = (unsigned short*)d_ws;

    unsigned short* Qb  = ws;
    unsigned short* Kb  = ws + 4194304;
    unsigned short* Vtb = ws + 8388608;
    unsigned short* Yb  = ws + 12582912;
    unsigned short* WaT = Yb;                      // W_attn^T during QKV only
    unsigned short* WpT = Qb;                      // W_proj^T after attn (Q dead)
    unsigned short* xb  = (unsigned short*)d_out;  // x bf16; overwritten by proj

    prep_a<<<dim3(2816), dim3(256), 0, stream>>>(x, xb, Wa, WaT);
    mm_bt<0><<<dim3(64, 12), dim3(256), 0, stream>>>(xb, WaT, (void*)ws);
    attn_mfma<<<dim3(512), dim3(256), 0, stream>>>(Qb, Kb, Vtb, Yb);
    transpose_wp<<<dim3(16, 16), dim3(256), 0, stream>>>(Wp, WpT);
    mm_bt<1><<<dim3(64, 4), dim3(256), 0, stream>>>(Yb, WpT, (void*)out);
}

// Round 5
// 165.694 us; speedup vs baseline: 1.1334x; 1.1334x over previous
//
#include <hip/hip_runtime.h>
#include <hip/hip_bf16.h>
#include <stdint.h>

// B=2, T=4096, C=512, H=8, D=64. Inputs fp32, output fp32, internals bf16.
// ws (bf16 elems), 32 MiB:
//   Q  [0        .. 4194304)   [B,H,T,D]  (pre-scaled by 0.125*log2e)
//   K  [4194304  .. 8388608)   [B,H,T,D]
//   Vt [8388608  .. 12582912)  [B,H,D,T]
//   Y  [12582912 .. 16777216)  [B,T,C]    (WaT here during QKV; clobbered by attn)
// WpT -> Q region after attn (Q dead). xb (x bf16) in d_out until proj overwrites.

typedef __attribute__((ext_vector_type(8))) short short8;
typedef __attribute__((ext_vector_type(4))) float floatx4;
typedef __attribute__((ext_vector_type(16))) float floatx16;
#if __has_builtin(__builtin_amdgcn_permlane32_swap)
typedef __attribute__((ext_vector_type(2))) unsigned int uint2v;
#define HAVE_PLSWAP 1
#else
#define HAVE_PLSWAP 0
#endif

__device__ __forceinline__ unsigned short f2bf(float f) {
    unsigned int x = __float_as_uint(f);
    unsigned int r = x + 0x7fffu + ((x >> 16) & 1u);
    return (unsigned short)(r >> 16);
}

__device__ __forceinline__ unsigned int pk_bf16(float a, float b) {
    __hip_bfloat162 p = __float22bfloat162_rn(make_float2(a, b));  // v_cvt_pk_bf16_f32
    return *reinterpret_cast<unsigned int*>(&p);
}

// sum of the two bf16 values packed in w (exactly the values PV will consume)
__device__ __forceinline__ float bfsum2(unsigned int w) {
    return __uint_as_float(w << 16) + __uint_as_float(w & 0xffff0000u);
}

// ---------------- P0: fused prep: convert x (blocks 0..2047) + W_attn^T (2048..2815) --
__global__ __launch_bounds__(256) void prep_a(
    const float* __restrict__ x, unsigned short* __restrict__ xb,
    const float* __restrict__ Wa, unsigned short* __restrict__ WaT)
{
    const int bid = blockIdx.x;
    const int tid = threadIdx.x;
    if (bid < 2048) {
        size_t i = ((size_t)bid * 256 + tid) * 8;
        float4 a = *reinterpret_cast<const float4*>(x + i);
        float4 b = *reinterpret_cast<const float4*>(x + i + 4);
        unsigned short o[8] = {f2bf(a.x), f2bf(a.y), f2bf(a.z), f2bf(a.w),
                               f2bf(b.x), f2bf(b.y), f2bf(b.z), f2bf(b.w)};
        *reinterpret_cast<uint4*>(xb + i) = *reinterpret_cast<uint4*>(o);
    } else {
        __shared__ unsigned short tile[32][34];
        const int t2 = bid - 2048;           // 48 n-tiles x 16 k-tiles
        const int n0 = (t2 % 48) * 32, k0 = (t2 / 48) * 32;
        const int tx = tid & 31, ty = tid >> 5;
        #pragma unroll
        for (int p = 0; p < 4; ++p)
            tile[tx][ty + p * 8] = f2bf(Wa[(size_t)(k0 + ty + p * 8) * 1536 + n0 + tx]);
        __syncthreads();
        #pragma unroll
        for (int p = 0; p < 4; ++p)
            WaT[(size_t)(n0 + ty + p * 8) * 512 + k0 + tx] = tile[ty + p * 8][tx];
    }
}

// ---------------- P1: W_proj [512][512] fp32 -> WpT [512][512] bf16 -------------------
__global__ __launch_bounds__(256) void transpose_wp(
    const float* __restrict__ W, unsigned short* __restrict__ Wt)
{
    __shared__ unsigned short tile[32][34];
    const int tid = threadIdx.x;
    const int tx = tid & 31, ty = tid >> 5;
    const int n0 = blockIdx.x * 32, k0 = blockIdx.y * 32;
    #pragma unroll
    for (int p = 0; p < 4; ++p)
        tile[tx][ty + p * 8] = f2bf(W[(size_t)(k0 + ty + p * 8) * 512 + n0 + tx]);
    __syncthreads();
    #pragma unroll
    for (int p = 0; p < 4; ++p)
        Wt[(size_t)(n0 + ty + p * 8) * 512 + k0 + tx] = tile[ty + p * 8][tx];
}

// ---------------- MFMA GEMM (r16-proven): 128x128, BK=32, LDS dbuf, 1 barrier/iter ----
template<int EPI>
__global__ __launch_bounds__(256) void mm_bt(
    const unsigned short* __restrict__ A,
    const unsigned short* __restrict__ Bt,
    void* __restrict__ outp)
{
    __shared__ __align__(16) unsigned char smem[40960];

    const int tid  = threadIdx.x;
    const int wave = tid >> 6;
    const int lane = tid & 63;
    const int quad = lane >> 4;
    const int l16  = lane & 15;
    const int wr   = wave >> 1;
    const int wc   = wave & 1;
    const int m0 = blockIdx.x * 128;
    const int n0 = blockIdx.y * 128;

    floatx4 acc[4][4];
    #pragma unroll
    for (int i = 0; i < 4; ++i)
        #pragma unroll
        for (int j = 0; j < 4; ++j) acc[i][j] = (floatx4){0.f, 0.f, 0.f, 0.f};

    const int row = tid >> 1;
    const int cb  = (tid & 1) * 16;

    const unsigned short* ap = &A[(size_t)(m0 + row) * 512 + cb];
    const unsigned short* bp = &Bt[(size_t)(n0 + row) * 512 + cb];

    uint4 ra0 = *reinterpret_cast<const uint4*>(ap);
    uint4 ra1 = *reinterpret_cast<const uint4*>(ap + 8);
    uint4 rb0 = *reinterpret_cast<const uint4*>(bp);
    uint4 rb1 = *reinterpret_cast<const uint4*>(bp + 8);
    {
        auto Al = reinterpret_cast<unsigned short(*)[40]>(smem);
        auto Bl = reinterpret_cast<unsigned short(*)[40]>(smem + 10240);
        *reinterpret_cast<uint4*>(&Al[row][cb])     = ra0;
        *reinterpret_cast<uint4*>(&Al[row][cb + 8]) = ra1;
        *reinterpret_cast<uint4*>(&Bl[row][cb])     = rb0;
        *reinterpret_cast<uint4*>(&Bl[row][cb + 8]) = rb1;
    }

    for (int it = 0; it < 16; ++it) {
        __syncthreads();
        const int k0 = it * 32;
        if (it < 15) {
            ra0 = *reinterpret_cast<const uint4*>(ap + k0 + 32);
            ra1 = *reinterpret_cast<const uint4*>(ap + k0 + 40);
            rb0 = *reinterpret_cast<const uint4*>(bp + k0 + 32);
            rb1 = *reinterpret_cast<const uint4*>(bp + k0 + 40);
        }

        auto Al = reinterpret_cast<unsigned short(*)[40]>(smem + (it & 1) * 20480);
        auto Bl = reinterpret_cast<unsigned short(*)[40]>(smem + (it & 1) * 20480 + 10240);

        short8 af[4], bf[4];
        #pragma unroll
        for (int ti = 0; ti < 4; ++ti)
            af[ti] = *reinterpret_cast<const short8*>(&Al[wr * 64 + ti * 16 + l16][quad * 8]);
        #pragma unroll
        for (int tj = 0; tj < 4; ++tj)
            bf[tj] = *reinterpret_cast<const short8*>(&Bl[wc * 64 + tj * 16 + l16][quad * 8]);
        #pragma unroll
        for (int ti = 0; ti < 4; ++ti)
            #pragma unroll
            for (int tj = 0; tj < 4; ++tj)
                acc[ti][tj] = __builtin_amdgcn_mfma_f32_16x16x32_bf16(af[ti], bf[tj], acc[ti][tj], 0, 0, 0);

        if (it < 15) {
            auto An = reinterpret_cast<unsigned short(*)[40]>(smem + ((it + 1) & 1) * 20480);
            auto Bn = reinterpret_cast<unsigned short(*)[40]>(smem + ((it + 1) & 1) * 20480 + 10240);
            *reinterpret_cast<uint4*>(&An[row][cb])     = ra0;
            *reinterpret_cast<uint4*>(&An[row][cb + 8]) = ra1;
            *reinterpret_cast<uint4*>(&Bn[row][cb])     = rb0;
            *reinterpret_cast<uint4*>(&Bn[row][cb + 8]) = rb1;
        }
    }

    if (EPI == 0) {
        unsigned short* WS = (unsigned short*)outp;
        unsigned short* Qb  = WS;
        unsigned short* Kb  = WS + 4194304;
        unsigned short* Vtb = WS + 8388608;
        const int which = n0 >> 9;
        const int h = ((n0 + wc * 64) >> 6) & 7;

        if (which == 2) {
            auto Tr = reinterpret_cast<unsigned short(*)[80]>(smem);   // [256][80]
            __syncthreads();
            #pragma unroll
            for (int ti = 0; ti < 4; ++ti)
                #pragma unroll
                for (int tj = 0; tj < 4; ++tj) {
                    unsigned int lo = pk_bf16(acc[ti][tj][0], acc[ti][tj][1]);
                    unsigned int hi = pk_bf16(acc[ti][tj][2], acc[ti][tj][3]);
                    *reinterpret_cast<uint2*>(&Tr[(wave << 6) + tj * 16 + l16][ti * 16 + quad * 4])
                        = make_uint2(lo, hi);
                }
            const int b = m0 >> 12;
            const int bh = b * 8 + h;
            const int t0g = (m0 & 4095) + wr * 64;
            const int tseg = (lane & 7) * 8;
            #pragma unroll
            for (int p = 0; p < 8; ++p) {
                int dl = p * 8 + (lane >> 3);
                uint4 v = *reinterpret_cast<const uint4*>(&Tr[(wave << 6) + dl][tseg]);
                *reinterpret_cast<uint4*>(&Vtb[((size_t)(bh * 64 + dl)) * 4096 + t0g + tseg]) = v;
            }
        } else {
            const float sc = (which == 0) ? 0.18033688f : 1.0f;  // 0.125*log2(e)
            #pragma unroll
            for (int ti = 0; ti < 4; ++ti) {
                #pragma unroll
                for (int r = 0; r < 4; ++r) {
                    int m = m0 + wr * 64 + ti * 16 + quad * 4 + r;
                    int b = m >> 12, t = m & 4095;
                    int bh = b * 8 + h;
                    #pragma unroll
                    for (int tj = 0; tj < 4; ++tj) {
                        int d = tj * 16 + l16;
                        unsigned short val = f2bf(acc[ti][tj][r] * sc);
                        if (which == 0) Qb[((size_t)bh * 4096 + t) * 64 + d] = val;
                        else            Kb[((size_t)bh * 4096 + t) * 64 + d] = val;
                    }
                }
            }
        }
    } else {
        float* Out = (float*)outp;
        #pragma unroll
        for (int ti = 0; ti < 4; ++ti) {
            #pragma unroll
            for (int r = 0; r < 4; ++r) {
                int m = m0 + wr * 64 + ti * 16 + quad * 4 + r;
                #pragma unroll
                for (int tj = 0; tj < 4; ++tj) {
                    int n = n0 + wc * 64 + tj * 16 + l16;
                    Out[(size_t)m * 512 + n] = acc[ti][tj][r];
                }
            }
        }
    }
}

// ---------------- MFMA flash attention: r3 geometry + 32x32 split-K waves -------------
// Block = 64 q-rows, 256 threads, 1024 blocks (64 qb x 16 bh), balanced permutation,
// 4 blocks/CU resident (LDS 32 KB) -- the round-3 geometry that measured 25.6% occ.
// Wave (p = wave>>1, w = wave&1): q-rows m0+32p..+31 vs key half 32w..32w+31 of each
// tile. ALL 4 waves active every iteration, uniform kt = 0..qb (r4's idle-wave bug
// fixed). Per block-tile LDS: 32 ds_read_b128 + 16 staging writes (r3: ~104) -- the
// binding LDS pipe is cut 2.2x. P built in registers (r4-VERIFIED cvt_pk +
// permlane32_swap, C-layouts m74/m101); partial O + rowsum combined across each wave
// pair ONCE at the end via LDS reuse of Kc/Vc (16 KB bounce, amortized over qb tiles).
__global__ __launch_bounds__(256) void attn_mfma(
    const unsigned short* __restrict__ Q,
    const unsigned short* __restrict__ K,
    const unsigned short* __restrict__ Vt,
    unsigned short* __restrict__ Y)
{
    __shared__ __align__(16) unsigned short Kc[2][64][64];
    __shared__ __align__(16) unsigned short Vc[2][64][64];

    const int tid  = threadIdx.x;
    const int wave = tid >> 6;
    const int lane = tid & 63;
    const int l32  = lane & 31;
    const int hh   = lane >> 5;
    const int swz  = l32 & 7;
    const int p    = wave >> 1;      // q-half of block (rows m0+32p .. +31)
    const int w    = wave & 1;       // key-half of tile (keys 32w .. 32w+31)

    // balanced qb permutation (r3-proven): per-CU tile count = const 130
    const int bid = blockIdx.x;
    const int bh  = bid & 15;
    const int j   = (bid >> 4) & 15;
    const int g   = bid >> 8;
    const int qb  = (g == 0) ? j : (g == 1) ? (63 - j) : (g == 2) ? (16 + j) : (47 - j);
    const int m0  = qb * 64;

    const unsigned short* Qp = Q  + (size_t)bh * (4096 * 64);
    const unsigned short* Kp = K  + (size_t)bh * (4096 * 64);
    const unsigned short* Vp = Vt + (size_t)bh * (64 * 4096);

    // Q B-frags (pre-scaled upstream): col q = m0+32p+l32, k(d) = k16*16 + hh*8 + j
    short8 qf[4];
    #pragma unroll
    for (int k16 = 0; k16 < 4; ++k16)
        qf[k16] = *reinterpret_cast<const short8*>(
            &Qp[(size_t)(m0 + 32 * p + l32) * 64 + k16 * 16 + hh * 8]);

    floatx16 o0 = {0,0,0,0,0,0,0,0,0,0,0,0,0,0,0,0};   // O[q][d=l32]
    floatx16 o1 = {0,0,0,0,0,0,0,0,0,0,0,0,0,0,0,0};   // O[q][d=32+l32]
    float rs = 0.f;

    // staging: thread covers rows rr, rr+32 at 16B chunk cc; XOR-swizzled (r1-proven)
    const int rr  = tid >> 3;
    const int cc  = tid & 7;
    const int c0  = cc * 8;
    const int scs = ((cc ^ (rr & 7)) << 3);

    uint4 rk0 = *reinterpret_cast<const uint4*>(&Kp[(size_t)rr * 64 + c0]);
    uint4 rk1 = *reinterpret_cast<const uint4*>(&Kp[(size_t)(rr + 32) * 64 + c0]);
    uint4 rv0 = *reinterpret_cast<const uint4*>(&Vp[(size_t)rr * 4096 + c0]);
    uint4 rv1 = *reinterpret_cast<const uint4*>(&Vp[(size_t)(rr + 32) * 4096 + c0]);
    *reinterpret_cast<uint4*>(&Kc[0][rr][scs])      = rk0;
    *reinterpret_cast<uint4*>(&Kc[0][rr + 32][scs]) = rk1;
    *reinterpret_cast<uint4*>(&Vc[0][rr][scs])      = rv0;
    *reinterpret_cast<uint4*>(&Vc[0][rr + 32][scs]) = rv1;

    const int NT = qb + 1;
    for (int kt = 0; kt < NT; ++kt) {
        __syncthreads();
        const int cur = kt & 1;
        const int nxt = cur ^ 1;

        if (kt + 1 < NT) {   // prefetch next tile into registers
            const int jn = (kt + 1) * 64;
            rk0 = *reinterpret_cast<const uint4*>(&Kp[(size_t)(jn + rr) * 64 + c0]);
            rk1 = *reinterpret_cast<const uint4*>(&Kp[(size_t)(jn + rr + 32) * 64 + c0]);
            rv0 = *reinterpret_cast<const uint4*>(&Vp[(size_t)rr * 4096 + jn + c0]);
            rv1 = *reinterpret_cast<const uint4*>(&Vp[(size_t)(rr + 32) * 4096 + jn + c0]);
        }

        // only fully-masked case: pair 0's key-half 1 on the diagonal tile
        const bool active = (kt < qb) || (w == 0) || (p == 1);
        if (active) {
            // ---- QK^T: S[key][q], A = K rows 32w+l32, B = Q ----
            floatx16 s = {0,0,0,0,0,0,0,0,0,0,0,0,0,0,0,0};
            #pragma unroll
            for (int k16 = 0; k16 < 4; ++k16) {
                const int chs = ((2 * k16 + hh) ^ swz) << 3;
                short8 a = *reinterpret_cast<const short8*>(&Kc[cur][32 * w + l32][chs]);
                s = __builtin_amdgcn_mfma_f32_32x32x16_bf16(a, qf[k16], s, 0, 0, 0);
            }
            if (kt == qb) {   // diagonal: key_local = 32w + (r&3)+8*(r>>2)+4*hh
                const int ql = 32 * p + l32;
                #pragma unroll
                for (int r = 0; r < 16; ++r) {
                    const int kl = 32 * w + (r & 3) + 8 * (r >> 2) + 4 * hh;
                    s[r] = (kl <= ql) ? s[r] : -1e30f;
                }
            }
            #pragma unroll
            for (int r = 0; r < 16; ++r) s[r] = __builtin_amdgcn_exp2f(s[r]);

            // ---- P -> PV A-frags in registers (r4-verified construction) ----
            unsigned int A0 = pk_bf16(s[0],  s[1]),  B0 = pk_bf16(s[2],  s[3]);
            unsigned int A1 = pk_bf16(s[4],  s[5]),  B1 = pk_bf16(s[6],  s[7]);
            unsigned int A2 = pk_bf16(s[8],  s[9]),  B2 = pk_bf16(s[10], s[11]);
            unsigned int A3 = pk_bf16(s[12], s[13]), B3 = pk_bf16(s[14], s[15]);
            rs += bfsum2(A0) + bfsum2(B0) + bfsum2(A1) + bfsum2(B1)
                + bfsum2(A2) + bfsum2(B2) + bfsum2(A3) + bfsum2(B3);
            short8 pa[2];
#if HAVE_PLSWAP
            {
                uint2v rA = __builtin_amdgcn_permlane32_swap(A0, A1, false, false);
                uint2v rB = __builtin_amdgcn_permlane32_swap(B0, B1, false, false);
                uint4 u0 = make_uint4(rA[0], rB[0], rA[1], rB[1]);
                pa[0] = *reinterpret_cast<short8*>(&u0);
                rA = __builtin_amdgcn_permlane32_swap(A2, A3, false, false);
                rB = __builtin_amdgcn_permlane32_swap(B2, B3, false, false);
                uint4 u1 = make_uint4(rA[0], rB[0], rA[1], rB[1]);
                pa[1] = *reinterpret_cast<short8*>(&u1);
            }
#else
            {
                unsigned int pA0 = __shfl_xor((int)A0, 32), pA1 = __shfl_xor((int)A1, 32);
                unsigned int pB0 = __shfl_xor((int)B0, 32), pB1 = __shfl_xor((int)B1, 32);
                unsigned int pA2 = __shfl_xor((int)A2, 32), pA3 = __shfl_xor((int)A3, 32);
                unsigned int pB2 = __shfl_xor((int)B2, 32), pB3 = __shfl_xor((int)B3, 32);
                uint4 u0 = make_uint4(hh ? pA1 : A0, hh ? pB1 : B0,
                                      hh ? A1 : pA0, hh ? B1 : pB0);
                pa[0] = *reinterpret_cast<short8*>(&u0);
                uint4 u1 = make_uint4(hh ? pA3 : A2, hh ? pB3 : B2,
                                      hh ? A3 : pA2, hh ? B3 : pB2);
                pa[1] = *reinterpret_cast<short8*>(&u1);
            }
#endif

            // ---- PV: O[q][d] over key window 32w..32w+31; B = V[key][d] ----
            #pragma unroll
            for (int f = 0; f < 2; ++f) {
                const int chs = ((4 * w + 2 * f + hh) ^ swz) << 3;
                short8 b0 = *reinterpret_cast<const short8*>(&Vc[cur][l32][chs]);
                short8 b1 = *reinterpret_cast<const short8*>(&Vc[cur][32 + l32][chs]);
                o0 = __builtin_amdgcn_mfma_f32_32x32x16_bf16(pa[f], b0, o0, 0, 0, 0);
                o1 = __builtin_amdgcn_mfma_f32_32x32x16_bf16(pa[f], b1, o1, 0, 0, 0);
            }
        }

        if (kt + 1 < NT) {   // stage prefetched tile into the idle buffer
            *reinterpret_cast<uint4*>(&Kc[nxt][rr][scs])      = rk0;
            *reinterpret_cast<uint4*>(&Kc[nxt][rr + 32][scs]) = rk1;
            *reinterpret_cast<uint4*>(&Vc[nxt][rr][scs])      = rv0;
            *reinterpret_cast<uint4*>(&Vc[nxt][rr + 32][scs]) = rv1;
        }
    }

    // ---- epilogue: combine partial O + rowsum across each wave pair (once) ----
    __syncthreads();                                       // all tile reads done
    float* Ob  = reinterpret_cast<float*>(&Kc[0][0][0]);   // [p][w][qloc][32] = 16 KB
    float* Wsf = reinterpret_cast<float*>(&Vc[0][0][0]);   // [p][w][32] rowsums
    float tot = rs + __shfl_xor(rs, 32);
    if (lane < 32) Wsf[(p * 2 + w) * 32 + l32] = tot;
    #pragma unroll
    for (int r = 0; r < 16; ++r) {                         // give away the partner half
        const int qloc = (r & 3) + 8 * (r >> 2) + 4 * hh;
        Ob[((p * 2 + w) * 32 + qloc) * 32 + l32] = w ? o0[r] : o1[r];
    }
    __syncthreads();

    const int b = bh >> 3, h = bh & 7;
    #pragma unroll
    for (int gg = 0; gg < 4; ++gg) {
        float4 a4 = *reinterpret_cast<const float4*>(&Wsf[(p * 2 + 0) * 32 + 8 * gg + 4 * hh]);
        float4 b4 = *reinterpret_cast<const float4*>(&Wsf[(p * 2 + 1) * 32 + 8 * gg + 4 * hh]);
        const float ivv[4] = {1.f / (a4.x + b4.x), 1.f / (a4.y + b4.y),
                              1.f / (a4.z + b4.z), 1.f / (a4.w + b4.w)};
        #pragma unroll
        for (int rsub = 0; rsub < 4; ++rsub) {
            const int r = gg * 4 + rsub;
            const int qloc = 8 * gg + 4 * hh + rsub;
            const float part = Ob[((p * 2 + (1 - w)) * 32 + qloc) * 32 + l32];
            const float mine = w ? o1[r] : o0[r];
            const int t = m0 + 32 * p + qloc;
            Y[((size_t)(b * 4096 + t)) * 512 + h * 64 + 32 * w + l32]
                = f2bf((mine + part) * ivv[rsub]);
        }
    }
}

extern "C" void kernel_launch(void* const* d_in, const int* in_sizes, int n_in,
                              void* d_out, int out_size, void* d_ws, size_t ws_size,
                              hipStream_t stream) {
    const float* x  = (const float*)d_in[0];
    const float* Wa = (const float*)d_in[1];
    const float* Wp = (const float*)d_in[2];
    float* out = (float*)d_out;
    unsigned short* ws = (unsigned short*)d_ws;

    unsigned short* Qb  = ws;
    unsigned short* Kb  = ws + 4194304;
    unsigned short* Vtb = ws + 8388608;
    unsigned short* Yb  = ws + 12582912;
    unsigned short* WaT = Yb;                      // W_attn^T during QKV only
    unsigned short* WpT = Qb;                      // W_proj^T after attn (Q dead)
    unsigned short* xb  = (unsigned short*)d_out;  // x bf16; overwritten by proj

    prep_a<<<dim3(2816), dim3(256), 0, stream>>>(x, xb, Wa, WaT);
    mm_bt<0><<<dim3(64, 12), dim3(256), 0, stream>>>(xb, WaT, (void*)ws);
    attn_mfma<<<dim3(1024), dim3(256), 0, stream>>>(Qb, Kb, Vtb, Yb);
    transpose_wp<<<dim3(16, 16), dim3(256), 0, stream>>>(Wp, WpT);
    mm_bt<1><<<dim3(64, 4), dim3(256), 0, stream>>>(Yb, WpT, (void*)out);
}